// Round 1
// baseline (459.273 us; speedup 1.0000x reference)
//
#include <hip/hip_runtime.h>

// DigitCaps dynamic routing, B=256 R=192 C=96 O=16 I=20. fp32 in/out.
// u_hat never materialized. 6 dispatches:
//   prep: W->WtT bf16 k-major; X->Xk + xT; bij=0 (c-major); tile counters=0
//   gemm1+redsq (x3): 128m x 64n tile, split-K=15, grid (2,24,15)=720;
//     A async global_load_lds(16B); B: it0 fully async, else reg-prefetch +
//     wave-local softmax scale at LDS-write; double LDS; partials bf16
//     P^T[z][n][b]. Last-arriver block per (x,y) tile (atomic counter,
//     threadfence release/acquire, no spin) reduces 15 z-partials + squash
//     -> vT/out in its epilogue. Tile is squash-self-contained (4 full caps).
//   gemm2_agree (x2): 128x64 tile, grid (30,24), fully async staging;
//     agreement in epilogue vs WtT, atomicAdd bij

#define R_ 192
#define C_ 96
#define O_ 16
#define I_ 20
#define B_ 256
#define K1 3840   // R*I
#define N_ 1536   // C*O
#define ZSPLIT 15
#define KCH 256       // K1/ZSPLIT; 4 iters of BK=64 (2x BK32 sub-tiles)
#define STILE 393216  // N_*B_ elements per z-slice

typedef unsigned short u16;
typedef __attribute__((ext_vector_type(8))) short short8;
typedef __attribute__((ext_vector_type(4))) float floatx4;

__device__ inline float bf2f(u16 h) {
  union { unsigned int u; float f; } x; x.u = ((unsigned int)h) << 16; return x.f;
}
__device__ inline u16 f2bf(float f) {
  union { float f; unsigned int u; } x; x.f = f;
  unsigned int r = x.u + 0x7FFFu + ((x.u >> 16) & 1u);
  return (u16)(r >> 16);
}
__device__ inline unsigned int pack2(float a, float b) {
  return (unsigned int)f2bf(a) | ((unsigned int)f2bf(b) << 16);
}
// async 16B/lane global->LDS; lds base wave-uniform (lane scatters +16B)
__device__ inline void async16(const u16* g, u16* l) {
  __builtin_amdgcn_global_load_lds(
      (__attribute__((address_space(1))) void*)(unsigned long long)g,
      (__attribute__((address_space(3))) void*)(unsigned int)(unsigned long long)l,
      16, 0, 0);
}

// ---- fused prep: WtT gather (5760 blocks, 4 elems/thr); X cast+transpose
// (240); bij=0 c-major (18); tile counters=0 (1)
__global__ void k_prep(const float* __restrict__ W, const float* __restrict__ X,
                       u16* __restrict__ WtT, u16* __restrict__ Xk,
                       u16* __restrict__ xT, float* __restrict__ bij,
                       int* __restrict__ cnt) {
  int bid = blockIdx.x;
  if (bid < 5760) {
    int t = (bid * 256 + threadIdx.x) << 2;    // 4-group stays in one n
    int n = t / K1, k = t - n * K1;
    int c = n >> 4, o = n & 15;
    const float* Wn = W + (size_t)(c * O_ + o) * I_;
    u16 h[4];
    #pragma unroll
    for (int e = 0; e < 4; ++e) {
      int ke = k + e, r = ke / I_, i = ke - r * I_;
      h[e] = f2bf(Wn[(size_t)r * (C_ * O_ * I_) + i]);
    }
    ushort4 o4; o4.x = h[0]; o4.y = h[1]; o4.z = h[2]; o4.w = h[3];
    *(ushort4*)&WtT[t] = o4;
  } else if (bid < 6000) {
    __shared__ u16 tile[64][72];
    int idx = bid - 5760;
    int kb = (idx % 60) << 6, bb = (idx / 60) << 6;
    int brow = threadIdx.x >> 4;          // 0..15
    int kq = (threadIdx.x & 15) << 2;     // 0..60 step 4
    #pragma unroll
    for (int p = 0; p < 4; ++p) {
      int bl = p * 16 + brow;
      float4 v = *(const float4*)(X + (size_t)(bb + bl) * K1 + kb + kq);
      ushort4 h;
      h.x = f2bf(v.x); h.y = f2bf(v.y); h.z = f2bf(v.z); h.w = f2bf(v.w);
      *(ushort4*)(Xk + (size_t)(bb + bl) * K1 + kb + kq) = h;
      tile[kq + 0][bl] = h.x;
      tile[kq + 1][bl] = h.y;
      tile[kq + 2][bl] = h.z;
      tile[kq + 3][bl] = h.w;
    }
    __syncthreads();
    int kr = threadIdx.x >> 3;            // 0..31
    int bq = (threadIdx.x & 7) << 3;      // 0..56 step 8
    #pragma unroll
    for (int q = 0; q < 2; ++q) {
      int kl = q * 32 + kr;
      *(uint4*)(xT + (size_t)(kb + kl) * B_ + bb + bq) = *(const uint4*)&tile[kl][bq];
    }
  } else if (bid < 6018) {
    int t = ((bid - 6000) * 256 + threadIdx.x) << 2;  // bij: 18,432 floats
    if (t < R_ * C_) *(float4*)&bij[t] = (float4){0.f, 0.f, 0.f, 0.f};
  } else {
    if (threadIdx.x < 3 * 48) cnt[threadIdx.x] = 0;   // per-iter tile counters
  }
}

// scale 8 k-contiguous bf16 (global k = kg..kg+7) by softmax row(s)
__device__ inline uint4 scale_b8(uint4 raw, int kg, const float* smrow) {
  int r0 = kg / I_;
  int bnd = (r0 + 1) * I_ - kg;                // elements j<bnd use r0
  float s0 = smrow[r0];
  float s1 = smrow[(r0 + 1 < R_) ? r0 + 1 : R_ - 1];
  union { uint4 q; u16 h[8]; } u; u.q = raw;
  #pragma unroll
  for (int j = 0; j < 8; ++j)
    u.h[j] = f2bf(bf2f(u.h[j]) * ((j < bnd) ? s0 : s1));
  return u.q;
}

// ---- GEMM1: P^T[z][n][b] bf16 = (Xk[256,3840] x (c*WtT)[1536,3840]^T),
// k-chunk z (256 = 4 x BK64; each BK64 = 2 BK32 sub-tiles, ONE barrier).
// 128m x 64n tile, 4 waves of 64x32, grid (2,24,15)=720.
// Fused split-K reduce + squash: last z-block to finish tile (x,y) reduces.
__global__ __launch_bounds__(256, 3) void gemm1(
    const u16* __restrict__ A, const u16* __restrict__ Bt,
    const float* __restrict__ bij, u16* __restrict__ P, int doScale,
    float* __restrict__ out, u16* __restrict__ vT, int* __restrict__ cnt,
    float preScale, int last, int itIdx) {
  __shared__ union SH {
    struct {
      u16 As[2][2][128 * 32];   // 32 KB
      u16 Bs[2][2][64 * 32];    // 16 KB
      float sm[4][192];         // 3 KB
    } g;
    struct {
      float s[64][129];         // s_j tile, padded vs bank conflicts
      float f[4][128];          // squash factor per (capsule, b)
    } r;
  } sh;
  __shared__ int lastFlag;
  int tid = threadIdx.x;
  int w = tid >> 6, lane = tid & 63;
  if (doScale) {  // wave-local softmax: wave w owns capsule (by<<2)+w
    int c = (blockIdx.y << 2) + w;
    float e0 = bij[c * R_ + lane];
    float e1 = bij[c * R_ + lane + 64];
    float e2 = bij[c * R_ + lane + 128];
    float mx = fmaxf(e0, fmaxf(e1, e2));
    #pragma unroll
    for (int off = 32; off > 0; off >>= 1) mx = fmaxf(mx, __shfl_xor(mx, off));
    e0 = expf(e0 - mx); e1 = expf(e1 - mx); e2 = expf(e2 - mx);
    float s = e0 + e1 + e2;
    #pragma unroll
    for (int off = 32; off > 0; off >>= 1) s += __shfl_xor(s, off);
    float inv = 1.0f / s;
    sh.g.sm[w][lane] = e0 * inv;
    sh.g.sm[w][lane + 64] = e1 * inv;
    sh.g.sm[w][lane + 128] = e2 * inv;
  }

  long m0 = (long)blockIdx.x * 128, n0 = (long)blockIdx.y * 64;
  int k0 = blockIdx.z * KCH;
  const u16* Ab = A + m0 * K1 + k0;
  const u16* Bb = Bt + n0 * K1 + k0;
  int srow = tid >> 2;              // 0..63
  int scol = (tid & 3) << 3;        // 0,8,16,24
  int wm = (w >> 1) << 6, wn = (w & 1) << 5;
  int quad = lane >> 4, lrow = lane & 15;
  int wb = w << 9;                  // wave-uniform LDS base (u16 elems)
  const u16* Ag0 = Ab + (long)srow * K1 + scol;
  const u16* Ag1 = Ab + (long)(srow + 64) * K1 + scol;
  const u16* Bg0 = Bb + (long)srow * K1 + scol;
  floatx4 acc[4][2];
  #pragma unroll
  for (int a = 0; a < 4; ++a)
    #pragma unroll
    for (int b = 0; b < 2; ++b) acc[a][b] = (floatx4){0.f, 0.f, 0.f, 0.f};

  // kt=0 staging: both sub-tiles
  async16(Ag0, &sh.g.As[0][0][wb]);
  async16(Ag1, &sh.g.As[0][0][2048 + wb]);
  async16(Ag0 + 32, &sh.g.As[0][1][wb]);
  async16(Ag1 + 32, &sh.g.As[0][1][2048 + wb]);
  uint4 b0, b1;
  if (doScale) {
    b0 = *(const uint4*)Bg0;
    b1 = *(const uint4*)(Bg0 + 32);
  } else {
    async16(Bg0, &sh.g.Bs[0][0][wb]);
    async16(Bg0 + 32, &sh.g.Bs[0][1][wb]);
  }
  __syncthreads();                   // asyncs drained; sm visible

  int p = 0;
  for (int kt = 0; kt < 4; ++kt) {
    if (doScale) {                   // capsule of B row srow == w (tid>>6)
      int kg = k0 + (kt << 6) + scol;
      ((uint4*)sh.g.Bs[p][0])[tid] = scale_b8(b0, kg, &sh.g.sm[w][0]);
      ((uint4*)sh.g.Bs[p][1])[tid] = scale_b8(b1, kg + 32, &sh.g.sm[w][0]);
      __syncthreads();               // Bs[p] visible; As[p] asyncs complete
    } else if (kt > 0) {
      __syncthreads();               // buf p asyncs complete
    }
    if (kt + 1 < 4) {                // prefetch escapes the barrier drain
      int kk = (kt + 1) << 6;
      async16(Ag0 + kk, &sh.g.As[p ^ 1][0][wb]);
      async16(Ag1 + kk, &sh.g.As[p ^ 1][0][2048 + wb]);
      async16(Ag0 + kk + 32, &sh.g.As[p ^ 1][1][wb]);
      async16(Ag1 + kk + 32, &sh.g.As[p ^ 1][1][2048 + wb]);
      if (doScale) {
        b0 = *(const uint4*)(Bg0 + kk);
        b1 = *(const uint4*)(Bg0 + kk + 32);
      } else {
        async16(Bg0 + kk, &sh.g.Bs[p ^ 1][0][wb]);
        async16(Bg0 + kk + 32, &sh.g.Bs[p ^ 1][1][wb]);
      }
    }
    #pragma unroll
    for (int s = 0; s < 2; ++s) {
      short8 af[4], bfr[2];
      #pragma unroll
      for (int ms = 0; ms < 4; ++ms)
        af[ms] = *(const short8*)&sh.g.As[p][s][(wm + ms * 16 + lrow) * 32 + (quad << 3)];
      #pragma unroll
      for (int ns = 0; ns < 2; ++ns)
        bfr[ns] = *(const short8*)&sh.g.Bs[p][s][(wn + ns * 16 + lrow) * 32 + (quad << 3)];
      #pragma unroll
      for (int ms = 0; ms < 4; ++ms)
        #pragma unroll
        for (int ns = 0; ns < 2; ++ns)
          acc[ms][ns] = __builtin_amdgcn_mfma_f32_16x16x32_bf16(
              af[ms], bfr[ns], acc[ms][ns], 0, 0, 0);
    }
    p ^= 1;
  }
  // transposed bf16 store: P[z][n*256 + b]; lane holds 4 consecutive b
  size_t zb = (size_t)blockIdx.z * (size_t)STILE;
  #pragma unroll
  for (int ms = 0; ms < 4; ++ms)
    #pragma unroll
    for (int ns = 0; ns < 2; ++ns) {
      int b = (int)m0 + wm + ms * 16 + (quad << 2);
      int n = (int)n0 + wn + ns * 16 + lrow;
      uint2 pk;
      pk.x = pack2(acc[ms][ns][0], acc[ms][ns][1]);
      pk.y = pack2(acc[ms][ns][2], acc[ms][ns][3]);
      *(uint2*)&P[zb + (size_t)n * B_ + b] = pk;
    }

  // ---- last-arriver split-K reduce + squash for tile (x,y). Release: all
  // threads fence, barrier, then one atomicAdd. No spin -> deadlock-free.
  __threadfence();
  __syncthreads();
  if (tid == 0) {
    int old = atomicAdd(&cnt[itIdx * 48 + (int)blockIdx.x * 24 + (int)blockIdx.y], 1);
    lastFlag = (old == ZSPLIT - 1) ? 1 : 0;
  }
  __syncthreads();
  if (!lastFlag) return;
  __threadfence();                   // acquire: other z-blocks' P visible

  int tb = (int)m0, tn = (int)n0;
  // phase A: sum 15 z-partials, 1024 tasks (64 n x 16 b-groups of 8)
  #pragma unroll
  for (int k = 0; k < 4; ++k) {
    int task = tid + (k << 8);
    int n = task >> 4, bg = task & 15;
    const u16* base = P + (size_t)(tn + n) * B_ + tb + (bg << 3);
    float a[8];
    #pragma unroll
    for (int j = 0; j < 8; ++j) a[j] = 0.f;
    for (int z = 0; z < ZSPLIT; ++z) {
      union { uint4 q; u16 h[8]; } u;
      u.q = *(const uint4*)(base + (size_t)z * STILE);
      #pragma unroll
      for (int j = 0; j < 8; ++j) a[j] += bf2f(u.h[j]);
    }
    #pragma unroll
    for (int j = 0; j < 8; ++j) sh.r.s[n][(bg << 3) + j] = a[j] * preScale;
  }
  __syncthreads();
  // phase B1: nsq over o per (capsule, b) -> squash factor f
  {
    int cB = tid >> 6, bb = tid & 63;
    #pragma unroll
    for (int hh = 0; hh < 2; ++hh) {
      int b = bb + (hh << 6);
      float nsq = 0.f;
      #pragma unroll
      for (int o = 0; o < 16; ++o) {
        float v = sh.r.s[(cB << 4) + o][b];
        nsq += v * v;
      }
      sh.r.f[cB][b] = nsq / ((1.0f + nsq) * sqrtf(nsq));
    }
  }
  __syncthreads();
  if (last) {
    // out[b][n] fp32, coalesced: 16-lane groups write 16 consecutive float4
    #pragma unroll
    for (int k = 0; k < 8; ++k) {
      int task = tid + (k << 8);
      int bl = task >> 4, nq = task & 15;
      int n = nq << 2, cc = n >> 4;
      float fv = sh.r.f[cc][bl];
      float4 v;
      v.x = sh.r.s[n + 0][bl] * fv;
      v.y = sh.r.s[n + 1][bl] * fv;
      v.z = sh.r.s[n + 2][bl] * fv;
      v.w = sh.r.s[n + 3][bl] * fv;
      *(float4*)(out + (size_t)(tb + bl) * N_ + tn + n) = v;
    }
  } else {
    // vT[n][b] bf16, coalesced uint4 (8 b per store)
    #pragma unroll
    for (int k = 0; k < 4; ++k) {
      int task = tid + (k << 8);
      int n = task >> 4, bg = task & 15;
      int cc = n >> 4, bs = bg << 3;
      uint4 o4;
      unsigned int* po = (unsigned int*)&o4;
      #pragma unroll
      for (int j = 0; j < 4; ++j) {
        float lo = sh.r.s[n][bs + 2 * j] * sh.r.f[cc][bs + 2 * j];
        float hi = sh.r.s[n][bs + 2 * j + 1] * sh.r.f[cc][bs + 2 * j + 1];
        po[j] = pack2(lo, hi);
      }
      *(uint4*)&vT[(size_t)(tn + n) * B_ + tb + bs] = o4;
    }
  }
}

// ---- GEMM2 + agreement fused, 128m x 64n tile, grid (30,24), K=256 =
// 4 x BK64 (2 BK32 sub-tiles per barrier), fully async staging.
__global__ __launch_bounds__(256) void gemm2_agree(
    const u16* __restrict__ A, const u16* __restrict__ Bt,
    const u16* __restrict__ WtT, float* __restrict__ bij) {
  const int K = 256;
  __shared__ u16 As[2][2][128 * 32];
  __shared__ u16 Bs[2][2][64 * 32];
  int tid = threadIdx.x;
  long m0 = (long)blockIdx.x * 128, n0 = (long)blockIdx.y * 64;
  const u16* Ab = A + m0 * K;
  const u16* Bb = Bt + n0 * K;
  int srow = tid >> 2;
  int scol = (tid & 3) << 3;
  int w = tid >> 6, lane = tid & 63;
  int wm = (w >> 1) << 6, wn = (w & 1) << 5;
  int quad = lane >> 4, lrow = lane & 15;
  int wb = w << 9;                  // wave-uniform LDS base (u16 elems)
  const u16* Ag0 = Ab + (long)srow * K + scol;
  const u16* Ag1 = Ab + (long)(srow + 64) * K + scol;
  const u16* Bg0 = Bb + (long)srow * K + scol;
  floatx4 acc[4][2];
  #pragma unroll
  for (int a = 0; a < 4; ++a)
    #pragma unroll
    for (int b = 0; b < 2; ++b) acc[a][b] = (floatx4){0.f, 0.f, 0.f, 0.f};

  async16(Ag0, &As[0][0][wb]);
  async16(Ag1, &As[0][0][2048 + wb]);
  async16(Ag0 + 32, &As[0][1][wb]);
  async16(Ag1 + 32, &As[0][1][2048 + wb]);
  async16(Bg0, &Bs[0][0][wb]);
  async16(Bg0 + 32, &Bs[0][1][wb]);

  int p = 0;
  #pragma unroll
  for (int kt = 0; kt < 4; ++kt) {
    __syncthreads();                 // buf p asyncs complete
    if (kt + 1 < 4) {                // async prefetch escapes the drain
      int kk = (kt + 1) << 6;
      async16(Ag0 + kk, &As[p ^ 1][0][wb]);
      async16(Ag1 + kk, &As[p ^ 1][0][2048 + wb]);
      async16(Ag0 + kk + 32, &As[p ^ 1][1][wb]);
      async16(Ag1 + kk + 32, &As[p ^ 1][1][2048 + wb]);
      async16(Bg0 + kk, &Bs[p ^ 1][0][wb]);
      async16(Bg0 + kk + 32, &Bs[p ^ 1][1][wb]);
    }
    #pragma unroll
    for (int s = 0; s < 2; ++s) {
      short8 af[4], bfr[2];
      #pragma unroll
      for (int ms = 0; ms < 4; ++ms)
        af[ms] = *(const short8*)&As[p][s][(wm + ms * 16 + lrow) * 32 + (quad << 3)];
      #pragma unroll
      for (int ns = 0; ns < 2; ++ns)
        bfr[ns] = *(const short8*)&Bs[p][s][(wn + ns * 16 + lrow) * 32 + (quad << 3)];
      #pragma unroll
      for (int ms = 0; ms < 4; ++ms)
        #pragma unroll
        for (int ns = 0; ns < 2; ++ns)
          acc[ms][ns] = __builtin_amdgcn_mfma_f32_16x16x32_bf16(
              af[ms], bfr[ns], acc[ms][ns], 0, 0, 0);
    }
    p ^= 1;
  }
  // epilogue: per fragment, cols = one capsule c; 16 rows span <=2 routes r.
  #pragma unroll
  for (int ms = 0; ms < 4; ++ms) {
    int rowbase = (int)m0 + wm + ms * 16;          // wave-uniform
    int r_lo = rowbase / I_;
    int r_hi = (rowbase + 15) / I_;
    int bnd = (r_lo + 1) * I_;
    int rowl = rowbase + (quad << 2);
    #pragma unroll
    for (int ns = 0; ns < 2; ++ns) {
      int col = (int)n0 + wn + ns * 16 + lrow;
      uint2 wv = *(const uint2*)&WtT[(size_t)col * K1 + rowl];
      u16 h[4];
      h[0] = (u16)(wv.x & 0xffff); h[1] = (u16)(wv.x >> 16);
      h[2] = (u16)(wv.y & 0xffff); h[3] = (u16)(wv.y >> 16);
      float p0 = 0.f, p1 = 0.f;
      #pragma unroll
      for (int e = 0; e < 4; ++e) {
        float pr = acc[ms][ns][e] * bf2f(h[e]);
        if (rowl + e < bnd) p0 += pr; else p1 += pr;
      }
      #pragma unroll
      for (int off = 32; off > 0; off >>= 1) {
        p0 += __shfl_xor(p0, off);
        p1 += __shfl_xor(p1, off);
      }
      if (lane == 0) {
        int c = col >> 4;
        atomicAdd(&bij[c * R_ + r_lo], p0 * (1.0f / 256.0f));
        atomicAdd(&bij[c * R_ + r_hi], p1 * (1.0f / 256.0f));
      }
    }
  }
}

extern "C" void kernel_launch(void* const* d_in, const int* in_sizes, int n_in,
                              void* d_out, int out_size, void* d_ws, size_t ws_size,
                              hipStream_t stream) {
  const float* X = (const float*)d_in[0];   // fp32 [256,192,20]
  const float* W = (const float*)d_in[1];   // fp32 [192,96,16,20]
  float* out = (float*)d_out;               // fp32 [256,96,16]
  char* ws = (char*)d_ws;
  u16*  WtT = (u16*)(ws);                   // 11,796,480 B
  u16*  Xk  = (u16*)(ws + 11796480);        //  1,966,080 B
  u16*  xT  = (u16*)(ws + 13762560);        //  1,966,080 B
  u16*  vT  = (u16*)(ws + 15728640);        //    786,432 B
  u16*  Pb  = (u16*)(ws + 16515072);        // 15 z x 786,432 B = 11,796,480 B
  float* bij = (float*)(ws + 28311552);     //     73,728 B (c-major [c][r])
  int*  cnt = (int*)(ws + 28385280);        //        576 B (3 iters x 48 tiles)

  k_prep<<<6019, 256, 0, stream>>>(W, X, WtT, Xk, xT, bij, cnt);

  for (int it = 0; it < 3; ++it) {
    // s partials: M=256,N=1536,K=3840, grid (2,24,15)=720, 4 BK64 iters.
    // iter 0: no scale in gemm1; uniform softmax 1/192 applied in reduce.
    // last z-block per (x,y) tile reduces + squashes in its epilogue.
    gemm1<<<dim3(2, 24, ZSPLIT), 256, 0, stream>>>(
        Xk, WtT, bij, Pb, it > 0, out, vT, cnt,
        it == 0 ? (1.0f / 192.0f) : 1.0f, it == 2 ? 1 : 0, it);
    if (it < 2)
      gemm2_agree<<<dim3(30, 24), 256, 0, stream>>>(xT, vT, WtT, bij);
  }
}

// Round 2
// 173.558 us; speedup vs baseline: 2.6462x; 2.6462x over previous
//
#include <hip/hip_runtime.h>

// DigitCaps dynamic routing, B=256 R=192 C=96 O=16 I=20. fp32 in/out.
// u_hat never materialized, NO split-K partials (P eliminated). 6 dispatches:
//   prep: W->WtT bf16 k-major; X->Xk + xT; bij=0 (c-major)
//   gemm1+squash (x3): 32m x 32n tile (2 whole capsules), full K=3840 as
//     30 iters of BK128 (4 conflict-free 32k sub-tiles), double-buffered;
//     A always async global_load_lds(16B); B: it0 async, else reg-prefetch +
//     wave-local softmax scale at LDS-write. Squash fused in epilogue
//     (16-lane butterfly over the capsule's 16 o-columns) -> vT/out.
//     Grid (48 n-tiles, 8 m-tiles): n-major => the 8 m-blocks of one
//     n-slice land on one XCD (stride 48 % 8 == 0), B slice L2-resident.
//   gemm2_agree (x2): 128x64 tile, grid (30,24), fully async staging;
//     agreement in epilogue vs WtT, atomicAdd bij
// Lesson R1: cross-block fusion via __threadfence = per-block full-L2
// writeback storms (138us). Dispatch boundary IS the cheap bulk fence.

#define R_ 192
#define C_ 96
#define O_ 16
#define I_ 20
#define B_ 256
#define K1 3840   // R*I
#define N_ 1536   // C*O
#define NKT 30    // K1 / 128

typedef unsigned short u16;
typedef __attribute__((ext_vector_type(8))) short short8;
typedef __attribute__((ext_vector_type(4))) float floatx4;

__device__ inline float bf2f(u16 h) {
  union { unsigned int u; float f; } x; x.u = ((unsigned int)h) << 16; return x.f;
}
__device__ inline u16 f2bf(float f) {
  union { float f; unsigned int u; } x; x.f = f;
  unsigned int r = x.u + 0x7FFFu + ((x.u >> 16) & 1u);
  return (u16)(r >> 16);
}
__device__ inline unsigned int pack2(float a, float b) {
  return (unsigned int)f2bf(a) | ((unsigned int)f2bf(b) << 16);
}
// async 16B/lane global->LDS; lds base wave-uniform (lane scatters +16B)
__device__ inline void async16(const u16* g, u16* l) {
  __builtin_amdgcn_global_load_lds(
      (__attribute__((address_space(1))) void*)(unsigned long long)g,
      (__attribute__((address_space(3))) void*)(unsigned int)(unsigned long long)l,
      16, 0, 0);
}

// ---- fused prep: WtT gather (5760 blocks, 4 elems/thr); X cast+transpose
// (240); bij=0 c-major (18)
__global__ void k_prep(const float* __restrict__ W, const float* __restrict__ X,
                       u16* __restrict__ WtT, u16* __restrict__ Xk,
                       u16* __restrict__ xT, float* __restrict__ bij) {
  int bid = blockIdx.x;
  if (bid < 5760) {
    int t = (bid * 256 + threadIdx.x) << 2;    // 4-group stays in one n
    int n = t / K1, k = t - n * K1;
    int c = n >> 4, o = n & 15;
    const float* Wn = W + (size_t)(c * O_ + o) * I_;
    u16 h[4];
    #pragma unroll
    for (int e = 0; e < 4; ++e) {
      int ke = k + e, r = ke / I_, i = ke - r * I_;
      h[e] = f2bf(Wn[(size_t)r * (C_ * O_ * I_) + i]);
    }
    ushort4 o4; o4.x = h[0]; o4.y = h[1]; o4.z = h[2]; o4.w = h[3];
    *(ushort4*)&WtT[t] = o4;
  } else if (bid < 6000) {
    __shared__ u16 tile[64][72];
    int idx = bid - 5760;
    int kb = (idx % 60) << 6, bb = (idx / 60) << 6;
    int brow = threadIdx.x >> 4;          // 0..15
    int kq = (threadIdx.x & 15) << 2;     // 0..60 step 4
    #pragma unroll
    for (int p = 0; p < 4; ++p) {
      int bl = p * 16 + brow;
      float4 v = *(const float4*)(X + (size_t)(bb + bl) * K1 + kb + kq);
      ushort4 h;
      h.x = f2bf(v.x); h.y = f2bf(v.y); h.z = f2bf(v.z); h.w = f2bf(v.w);
      *(ushort4*)(Xk + (size_t)(bb + bl) * K1 + kb + kq) = h;
      tile[kq + 0][bl] = h.x;
      tile[kq + 1][bl] = h.y;
      tile[kq + 2][bl] = h.z;
      tile[kq + 3][bl] = h.w;
    }
    __syncthreads();
    int kr = threadIdx.x >> 3;            // 0..31
    int bq = (threadIdx.x & 7) << 3;      // 0..56 step 8
    #pragma unroll
    for (int q = 0; q < 2; ++q) {
      int kl = q * 32 + kr;
      *(uint4*)(xT + (size_t)(kb + kl) * B_ + bb + bq) = *(const uint4*)&tile[kl][bq];
    }
  } else {
    int t = ((bid - 6000) * 256 + threadIdx.x) << 2;  // bij: 18,432 floats
    if (t < R_ * C_) *(float4*)&bij[t] = (float4){0.f, 0.f, 0.f, 0.f};
  }
}

// scale 8 k-contiguous bf16 (global k = kg..kg+7) by softmax row(s)
__device__ inline uint4 scale_b8(uint4 raw, int kg, const float* smrow) {
  int r0 = kg / I_;
  int bnd = (r0 + 1) * I_ - kg;                // elements j<bnd use r0
  float s0 = smrow[r0];
  float s1 = smrow[(r0 + 1 < R_) ? r0 + 1 : R_ - 1];
  union { uint4 q; u16 h[8]; } u; u.q = raw;
  #pragma unroll
  for (int j = 0; j < 8; ++j)
    u.h[j] = f2bf(bf2f(u.h[j]) * ((j < bnd) ? s0 : s1));
  return u.q;
}

// ---- GEMM1 + fused squash. s[32b x 32n] = Xk[256,3840] x (c*WtT)^T, full K.
// 4 waves 2x2, each 16x16 (one whole capsule's 16 o per wave).
// BK=128 per iter = 4 sub-tiles [32 rows][32 k] (64B row stride: conflict-
// free). A staged by async16: wave w call0 covers sub(w>>1) rows (w&1)*16..;
// call1 same +2 subs. B: it0 identical async; else uint4 reg prefetch +
// softmax scale at ds_write (rows are n: capsule = row>>4).
__global__ __launch_bounds__(256) void gemm1(
    const u16* __restrict__ A, const u16* __restrict__ Bt,
    const float* __restrict__ bij, int doScale,
    float* __restrict__ out, u16* __restrict__ vT,
    float preScale, int last) {
  __shared__ u16 As[2][4][1024];   // 16 KB
  __shared__ u16 Bs[2][4][1024];   // 16 KB
  __shared__ float sm[2][192];     // 1.5 KB
  int tid = threadIdx.x;
  int w = tid >> 6, lane = tid & 63;
  if (doScale && w < 2) {  // wave w owns capsule 2*bx + w (softmax over 192 r)
    int c = ((int)blockIdx.x << 1) + w;
    float e0 = bij[c * R_ + lane];
    float e1 = bij[c * R_ + lane + 64];
    float e2 = bij[c * R_ + lane + 128];
    float mx = fmaxf(e0, fmaxf(e1, e2));
    #pragma unroll
    for (int off = 32; off > 0; off >>= 1) mx = fmaxf(mx, __shfl_xor(mx, off));
    e0 = expf(e0 - mx); e1 = expf(e1 - mx); e2 = expf(e2 - mx);
    float s = e0 + e1 + e2;
    #pragma unroll
    for (int off = 32; off > 0; off >>= 1) s += __shfl_xor(s, off);
    float inv = 1.0f / s;
    sm[w][lane] = e0 * inv;
    sm[w][lane + 64] = e1 * inv;
    sm[w][lane + 128] = e2 * inv;
  }

  long n0 = (long)blockIdx.x * 32, m0 = (long)blockIdx.y * 32;
  const u16* Ab = A + m0 * K1;
  const u16* Bb = Bt + n0 * K1;
  // async staging role: wave w, rows (w&1)*16+(lane>>2), sub base w>>1
  int srow = ((w & 1) << 4) + (lane >> 2);
  int scol = (lane & 3) << 3;
  int subA = w >> 1;
  int rb = (w & 1) << 9;            // LDS row-half base (elems), wave-uniform
  const u16* Ag = Ab + (long)srow * K1 + subA * 32 + scol;
  const u16* Bg = Bb + (long)srow * K1 + subA * 32 + scol;
  // doScale reg-staging role: row (n) = tid>>3, k-col (tid&7)*8 (+64)
  int rowb = tid >> 3;
  int kc = (tid & 7) << 3;
  const u16* Bgs = Bb + (long)rowb * K1 + kc;
  const float* smrow = &sm[rowb >> 4][0];
  int wm = (w >> 1) << 4, wn = (w & 1) << 4;
  int quad = lane >> 4, lrow = lane & 15;
  floatx4 acc = (floatx4){0.f, 0.f, 0.f, 0.f};

  // kt=0 staging
  async16(Ag, &As[0][subA][rb]);
  async16(Ag + 64, &As[0][subA + 2][rb]);
  uint4 pb0, pb1;
  if (doScale) {
    pb0 = *(const uint4*)Bgs;
    pb1 = *(const uint4*)(Bgs + 64);
  } else {
    async16(Bg, &Bs[0][subA][rb]);
    async16(Bg + 64, &Bs[0][subA + 2][rb]);
  }
  __syncthreads();                   // asyncs drained; sm visible

  int p = 0;
  for (int kt = 0; kt < NKT; ++kt) {
    if (doScale) {
      int kg = (kt << 7) + kc;
      int sub = kc >> 5;
      *(uint4*)&Bs[p][sub][rowb * 32 + (kc & 31)] = scale_b8(pb0, kg, smrow);
      *(uint4*)&Bs[p][sub + 2][rowb * 32 + (kc & 31)] = scale_b8(pb1, kg + 64, smrow);
      __syncthreads();               // Bs[p] visible; As[p] asyncs complete
    } else if (kt > 0) {
      __syncthreads();               // buf p asyncs complete
    }
    if (kt + 1 < NKT) {              // prefetch escapes the barrier drain
      int kk = (kt + 1) << 7;
      async16(Ag + kk, &As[p ^ 1][subA][rb]);
      async16(Ag + kk + 64, &As[p ^ 1][subA + 2][rb]);
      if (doScale) {
        pb0 = *(const uint4*)(Bgs + kk);
        pb1 = *(const uint4*)(Bgs + kk + 64);
      } else {
        async16(Bg + kk, &Bs[p ^ 1][subA][rb]);
        async16(Bg + kk + 64, &Bs[p ^ 1][subA + 2][rb]);
      }
    }
    #pragma unroll
    for (int s = 0; s < 4; ++s) {
      short8 af = *(const short8*)&As[p][s][(wm + lrow) * 32 + (quad << 3)];
      short8 bfr = *(const short8*)&Bs[p][s][(wn + lrow) * 32 + (quad << 3)];
      acc = __builtin_amdgcn_mfma_f32_16x16x32_bf16(af, bfr, acc, 0, 0, 0);
    }
    p ^= 1;
  }

  // ---- fused squash. Wave holds 16 b x 16 o of ONE capsule.
  // C/D layout: col(o) = lane&15, row(b) = quad*4 + e.
  float v0 = acc[0] * preScale, v1 = acc[1] * preScale;
  float v2 = acc[2] * preScale, v3 = acc[3] * preScale;
  float q0 = v0 * v0, q1 = v1 * v1, q2 = v2 * v2, q3 = v3 * v3;
  #pragma unroll
  for (int off = 1; off < 16; off <<= 1) {   // sum over 16 o-columns
    q0 += __shfl_xor(q0, off);
    q1 += __shfl_xor(q1, off);
    q2 += __shfl_xor(q2, off);
    q3 += __shfl_xor(q3, off);
  }
  v0 *= q0 / ((1.0f + q0) * sqrtf(q0));
  v1 *= q1 / ((1.0f + q1) * sqrtf(q1));
  v2 *= q2 / ((1.0f + q2) * sqrtf(q2));
  v3 *= q3 / ((1.0f + q3) * sqrtf(q3));
  int n = (int)n0 + wn + lrow;
  int b = (int)m0 + wm + (quad << 2);
  if (last) {
    out[(size_t)(b + 0) * N_ + n] = v0;
    out[(size_t)(b + 1) * N_ + n] = v1;
    out[(size_t)(b + 2) * N_ + n] = v2;
    out[(size_t)(b + 3) * N_ + n] = v3;
  } else {
    uint2 pk;
    pk.x = pack2(v0, v1);
    pk.y = pack2(v2, v3);
    *(uint2*)&vT[(size_t)n * B_ + b] = pk;
  }
}

// ---- GEMM2 + agreement fused, 128m x 64n tile, grid (30,24), K=256 =
// 4 x BK64 (2 BK32 sub-tiles per barrier), fully async staging.
__global__ __launch_bounds__(256) void gemm2_agree(
    const u16* __restrict__ A, const u16* __restrict__ Bt,
    const u16* __restrict__ WtT, float* __restrict__ bij) {
  const int K = 256;
  __shared__ u16 As[2][2][128 * 32];
  __shared__ u16 Bs[2][2][64 * 32];
  int tid = threadIdx.x;
  long m0 = (long)blockIdx.x * 128, n0 = (long)blockIdx.y * 64;
  const u16* Ab = A + m0 * K;
  const u16* Bb = Bt + n0 * K;
  int srow = tid >> 2;
  int scol = (tid & 3) << 3;
  int w = tid >> 6, lane = tid & 63;
  int wm = (w >> 1) << 6, wn = (w & 1) << 5;
  int quad = lane >> 4, lrow = lane & 15;
  int wb = w << 9;                  // wave-uniform LDS base (u16 elems)
  const u16* Ag0 = Ab + (long)srow * K + scol;
  const u16* Ag1 = Ab + (long)(srow + 64) * K + scol;
  const u16* Bg0 = Bb + (long)srow * K + scol;
  floatx4 acc[4][2];
  #pragma unroll
  for (int a = 0; a < 4; ++a)
    #pragma unroll
    for (int b = 0; b < 2; ++b) acc[a][b] = (floatx4){0.f, 0.f, 0.f, 0.f};

  async16(Ag0, &As[0][0][wb]);
  async16(Ag1, &As[0][0][2048 + wb]);
  async16(Ag0 + 32, &As[0][1][wb]);
  async16(Ag1 + 32, &As[0][1][2048 + wb]);
  async16(Bg0, &Bs[0][0][wb]);
  async16(Bg0 + 32, &Bs[0][1][wb]);

  int p = 0;
  #pragma unroll
  for (int kt = 0; kt < 4; ++kt) {
    __syncthreads();                 // buf p asyncs complete
    if (kt + 1 < 4) {                // async prefetch escapes the drain
      int kk = (kt + 1) << 6;
      async16(Ag0 + kk, &As[p ^ 1][0][wb]);
      async16(Ag1 + kk, &As[p ^ 1][0][2048 + wb]);
      async16(Ag0 + kk + 32, &As[p ^ 1][1][wb]);
      async16(Ag1 + kk + 32, &As[p ^ 1][1][2048 + wb]);
      async16(Bg0 + kk, &Bs[p ^ 1][0][wb]);
      async16(Bg0 + kk + 32, &Bs[p ^ 1][1][wb]);
    }
    #pragma unroll
    for (int s = 0; s < 2; ++s) {
      short8 af[4], bfr[2];
      #pragma unroll
      for (int ms = 0; ms < 4; ++ms)
        af[ms] = *(const short8*)&As[p][s][(wm + ms * 16 + lrow) * 32 + (quad << 3)];
      #pragma unroll
      for (int ns = 0; ns < 2; ++ns)
        bfr[ns] = *(const short8*)&Bs[p][s][(wn + ns * 16 + lrow) * 32 + (quad << 3)];
      #pragma unroll
      for (int ms = 0; ms < 4; ++ms)
        #pragma unroll
        for (int ns = 0; ns < 2; ++ns)
          acc[ms][ns] = __builtin_amdgcn_mfma_f32_16x16x32_bf16(
              af[ms], bfr[ns], acc[ms][ns], 0, 0, 0);
    }
    p ^= 1;
  }
  // epilogue: per fragment, cols = one capsule c; 16 rows span <=2 routes r.
  #pragma unroll
  for (int ms = 0; ms < 4; ++ms) {
    int rowbase = (int)m0 + wm + ms * 16;          // wave-uniform
    int r_lo = rowbase / I_;
    int r_hi = (rowbase + 15) / I_;
    int bnd = (r_lo + 1) * I_;
    int rowl = rowbase + (quad << 2);
    #pragma unroll
    for (int ns = 0; ns < 2; ++ns) {
      int col = (int)n0 + wn + ns * 16 + lrow;
      uint2 wv = *(const uint2*)&WtT[(size_t)col * K1 + rowl];
      u16 h[4];
      h[0] = (u16)(wv.x & 0xffff); h[1] = (u16)(wv.x >> 16);
      h[2] = (u16)(wv.y & 0xffff); h[3] = (u16)(wv.y >> 16);
      float p0 = 0.f, p1 = 0.f;
      #pragma unroll
      for (int e = 0; e < 4; ++e) {
        float pr = acc[ms][ns][e] * bf2f(h[e]);
        if (rowl + e < bnd) p0 += pr; else p1 += pr;
      }
      #pragma unroll
      for (int off = 32; off > 0; off >>= 1) {
        p0 += __shfl_xor(p0, off);
        p1 += __shfl_xor(p1, off);
      }
      if (lane == 0) {
        int c = col >> 4;
        atomicAdd(&bij[c * R_ + r_lo], p0 * (1.0f / 256.0f));
        atomicAdd(&bij[c * R_ + r_hi], p1 * (1.0f / 256.0f));
      }
    }
  }
}

extern "C" void kernel_launch(void* const* d_in, const int* in_sizes, int n_in,
                              void* d_out, int out_size, void* d_ws, size_t ws_size,
                              hipStream_t stream) {
  const float* X = (const float*)d_in[0];   // fp32 [256,192,20]
  const float* W = (const float*)d_in[1];   // fp32 [192,96,16,20]
  float* out = (float*)d_out;               // fp32 [256,96,16]
  char* ws = (char*)d_ws;
  u16*  WtT = (u16*)(ws);                   // 11,796,480 B
  u16*  Xk  = (u16*)(ws + 11796480);        //  1,966,080 B
  u16*  xT  = (u16*)(ws + 13762560);        //  1,966,080 B
  u16*  vT  = (u16*)(ws + 15728640);        //    786,432 B
  float* bij = (float*)(ws + 16515072);     //     73,728 B (c-major [c][r])

  k_prep<<<6018, 256, 0, stream>>>(W, X, WtT, Xk, xT, bij);

  for (int it = 0; it < 3; ++it) {
    // s_j + squash in one kernel: M=256,N=1536,K=3840 full-K, grid (48,8).
    // iter 0: no scale in gemm1; uniform softmax 1/192 via preScale.
    gemm1<<<dim3(48, 8), 256, 0, stream>>>(
        Xk, WtT, bij, it > 0, out, vT,
        it == 0 ? (1.0f / 192.0f) : 1.0f, it == 2 ? 1 : 0);
    if (it < 2)
      gemm2_agree<<<dim3(30, 24), 256, 0, stream>>>(xT, vT, WtT, bij);
  }
}